// Round 9
// baseline (923.925 us; speedup 1.0000x reference)
//
#include <hip/hip_runtime.h>

constexpr int S    = 256;
constexpr int D    = 32;
constexpr int NH   = 4;
constexpr int DH   = 8;
constexpr int DFF  = 64;
constexpr int NL   = 4;
constexpr int IND  = 58;
constexpr int HOUT = 25;
constexpr int TPB  = 384;  // 1 window/block, 6 waves -> 12 waves/CU (2 blocks)

typedef float  f2 __attribute__((ext_vector_type(2)));
typedef float  f4 __attribute__((ext_vector_type(4)));
typedef __fp16 h2 __attribute__((ext_vector_type(2)));
typedef __fp16 h4 __attribute__((ext_vector_type(4)));
typedef __fp16 h8 __attribute__((ext_vector_type(8)));

// LDS map (bytes), 64 KB total
constexpr int HOFF  = 0;      // h f16 [256][32] swizzled 8B-chunks; O reuses plain
constexpr int QKOFF = 16384;  // Q|K f16 [256 tok][64 feat], 16B-chunk XOR swizzle
constexpr int VOFF  = 49152;  // V^T 32 rows x 512 B, XOR-swizzled

__device__ __forceinline__ unsigned pk2(float a, float b) {
  h2 h = __builtin_amdgcn_cvt_pkrtz(a, b);
  return __builtin_bit_cast(unsigned, h);
}

// packed-fp32 dot (v_pk_fma_f32). All register-array loops must FULLY unroll
// (partial unroll -> scratch demotion, the round-3 251 MB regression).
template<int NF2>
__device__ __forceinline__ float dotp(const float* __restrict__ w,
                                      const float* __restrict__ v) {
  const f2* W = (const f2*)w;
  const f2* V = (const f2*)v;
  f2 a0 = {0.f, 0.f}, a1 = {0.f, 0.f};
#pragma unroll
  for (int i = 0; i < NF2; i += 2) a0 += V[i] * W[i];
#pragma unroll
  for (int i = 1; i < NF2; i += 2) a1 += V[i] * W[i];
  f2 s = a0 + a1;
  return s.x + s.y;
}

// tanh-approx GELU via exp (max dev ~3e-4, below bf16 floor; verified r7/r8)
__device__ __forceinline__ float gelu(float x) {
  float u = 1.5957691216057308f * fmaf(0.044715f * x * x, x, x);
  return x / (1.0f + __expf(-u));
}

__device__ __forceinline__ void lnorm(float* h, const float* __restrict__ g,
                                      const float* __restrict__ b) {
  float s = 0.f;
#pragma unroll
  for (int d = 0; d < D; ++d) s += h[d];
  const float m = s * (1.0f / D);
  float v = 0.f;
#pragma unroll
  for (int d = 0; d < D; ++d) { float c = h[d] - m; v = fmaf(c, c, v); }
  const float inv = rsqrtf(v * (1.0f / D) + 1e-5f);
#pragma unroll
  for (int d = 0; d < D; ++d) h[d] = (h[d] - m) * inv * g[d] + b[d];
}

__device__ __forceinline__ void embed_token(
    const float* __restrict__ xrow, int lay,
    const float* __restrict__ fpw, const float* __restrict__ fpb,
    const float* __restrict__ lemb, const float* __restrict__ fB,
    float* __restrict__ h) {
  float xr[IND];
  const f2* xv = (const f2*)xrow;
#pragma unroll
  for (int i = 0; i < 29; ++i) { f2 t = xv[i]; xr[2 * i] = t.x; xr[2 * i + 1] = t.y; }
  const float* le = lemb + lay * D;
  float pe[D];
#pragma unroll
  for (int k = 0; k < 16; ++k) {
    // sin(2*pi*t) = v_sin(fract(t)) -- hw sin takes revolutions; exact by
    // periodicity, arg-rounding error same order as the f32 reference's.
    float t = xr[0] * fB[k] + xr[1] * fB[16 + k] + xr[2] * fB[32 + k];
#if __has_builtin(__builtin_amdgcn_sinf) && __has_builtin(__builtin_amdgcn_cosf) && __has_builtin(__builtin_amdgcn_fractf)
    float u = __builtin_amdgcn_fractf(t);
    pe[k]      = __builtin_amdgcn_sinf(u);
    pe[16 + k] = __builtin_amdgcn_cosf(u);
#else
    float sv, cv;
    sincosf(6.2831853071795864f * (t - floorf(t)), &sv, &cv);
    pe[k] = sv; pe[16 + k] = cv;
#endif
  }
#pragma unroll
  for (int d = 0; d < D; ++d)
    h[d] = dotp<29>(fpw + d * IND, xr) + fpb[d] + le[d] + pe[d];
}

__device__ __forceinline__ void post_token(
    int l, float* __restrict__ h, const float* __restrict__ acc,
    const float* __restrict__ opw, const float* __restrict__ opb,
    const float* __restrict__ ln1g, const float* __restrict__ ln1b,
    const float* __restrict__ w1, const float* __restrict__ b1,
    const float* __restrict__ w2, const float* __restrict__ b2,
    const float* __restrict__ ln2g, const float* __restrict__ ln2b) {
  const float* Wo = opw + l * D * D;
  const float* Bo = opb + l * D;
#pragma unroll
  for (int o = 0; o < D; ++o) h[o] += dotp<16>(Wo + o * D, acc) + Bo[o];
  lnorm(h, ln1g + l * D, ln1b + l * D);
  const float* Wa = w1 + l * DFF * D;
  const float* Ba = b1 + l * DFF;
  float tt[DFF];
#pragma unroll
  for (int j = 0; j < DFF; ++j)
    tt[j] = gelu(dotp<16>(Wa + j * D, h) + Ba[j]);
  const float* Wb = w2 + l * D * DFF;
  const float* Bb = b2 + l * D;
#pragma unroll
  for (int d = 0; d < D; ++d) h[d] += dotp<32>(Wb + d * DFF, tt) + Bb[d];
  lnorm(h, ln2g + l * D, ln2b + l * D);
}

__device__ __forceinline__ void store_h16(unsigned char* sm, int tok,
                                          const float* __restrict__ h) {
#pragma unroll
  for (int c = 0; c < 8; ++c) {
    uint2 p{pk2(h[4 * c], h[4 * c + 1]), pk2(h[4 * c + 2], h[4 * c + 3])};
    *(uint2*)(sm + HOFF + tok * 64 + ((c ^ (tok & 7)) * 8)) = p;
  }
}

// One head's flash attention over it-tiles [it0, it0+itn).
__device__ __forceinline__ void attn_head(unsigned char* sm, int hh, int it0,
                                          int itn, int m, int quad, int qs) {
  h4 Af[16];  // K A-frags; quads 2,3 = dh 8->16 zero pad
#pragma unroll
  for (int jt = 0; jt < 16; ++jt) {
    const int tok = jt * 16 + m;
    uint2 a = *(const uint2*)(sm + QKOFF + tok * 128 +
                              (((4 + hh) ^ (tok & 7)) * 16) + qs * 8);
    if (quad >= 2) { a.x = 0u; a.y = 0u; }
    Af[jt] = __builtin_bit_cast(h4, a);
  }
  const int vbase = VOFF + (hh * 8 + (m & 7)) * 512;
  const int vkey  = (m & 7) << 1;

  for (int ii = 0; ii < itn; ++ii) {
    const int it = it0 + ii;
    const int ti = it * 16 + m;
    h4 Qf = *(const h4*)(sm + QKOFF + ti * 128 + ((hh ^ (ti & 7)) * 16) + qs * 8);
    f4 Of0 = {0.f, 0.f, 0.f, 0.f}, Of1 = {0.f, 0.f, 0.f, 0.f};
    float ls0 = 0.f, ls1 = 0.f;
#pragma unroll
    for (int jt = 0; jt < 16; ++jt) {
      // T[j,i] = K.Q^T: C col = i (lane&15), row = j (quad*4+r)
      f4 T = __builtin_amdgcn_mfma_f32_16x16x16f16(
                 Af[jt], Qf, (f4){0.f, 0.f, 0.f, 0.f}, 0, 0, 0);
      float e0 = __expf(T[0]), e1 = __expf(T[1]);
      float e2 = __expf(T[2]), e3 = __expf(T[3]);
      uint2 pu{pk2(e0, e1), pk2(e2, e3)};
      h4 P = __builtin_bit_cast(h4, pu);  // C-frag of T == A-frag of P
      h4 Bv = *(const h4*)(sm + vbase + (((jt * 4 + quad) ^ vkey) * 8));
      if (jt & 1) {  // dual accumulators: halve the PV/lsum dep chains
        ls1 += (e0 + e1) + (e2 + e3);
        Of1 = __builtin_amdgcn_mfma_f32_16x16x16f16(P, Bv, Of1, 0, 0, 0);
      } else {
        ls0 += (e0 + e1) + (e2 + e3);
        Of0 = __builtin_amdgcn_mfma_f32_16x16x16f16(P, Bv, Of0, 0, 0, 0);
      }
    }
    float lsum = ls0 + ls1;
    f4 Of = Of0 + Of1;
    lsum += __shfl_xor(lsum, 16);
    lsum += __shfl_xor(lsum, 32);
#pragma unroll
    for (int r = 0; r < 4; ++r) {
      float ls = __builtin_bit_cast(
          float, __builtin_amdgcn_ds_bpermute(
                     (quad * 4 + r) << 2, __builtin_bit_cast(int, lsum)));
      float o = Of[r] * __builtin_amdgcn_rcpf(ls);
      if (m < 8) {  // O -> plain [tok][32 f16] over dead h-f16 region
        const int t2 = it * 16 + quad * 4 + r;
        *(__fp16*)(sm + HOFF + t2 * 64 + (hh * 8 + m) * 2) = (__fp16)o;
      }
    }
  }
}

// (384,3): 12 waves/CU = 2 blocks -> VGPR cap ~170 >= ~120 natural (no spill).
__global__ void __launch_bounds__(TPB, 3)
spai_fused(const float* __restrict__ x,    const int*   __restrict__ layers,
           const float* __restrict__ fpw,  const float* __restrict__ fpb,
           const float* __restrict__ lemb, const float* __restrict__ fB,
           const float* __restrict__ ipw,  const float* __restrict__ ipb,
           const float* __restrict__ opw,  const float* __restrict__ opb,
           const float* __restrict__ ln1g, const float* __restrict__ ln1b,
           const float* __restrict__ w1,   const float* __restrict__ b1,
           const float* __restrict__ w2,   const float* __restrict__ b2,
           const float* __restrict__ ln2g, const float* __restrict__ ln2b,
           const float* __restrict__ nog,  const float* __restrict__ nob,
           const float* __restrict__ hw,   const float* __restrict__ hb,
           float* __restrict__ out) {
  __shared__ __align__(16) unsigned char sm[65536];
  const int tid  = threadIdx.x;
  const int lane = tid & 63;
  const int wave = tid >> 6;   // 0..5
  const int n16  = lane & 15;
  const int quad = lane >> 4;
  const int qs   = quad & 1;
  const size_t blk_tok = (size_t)blockIdx.x * S;

  float h[D];
  if (tid < S) {
    embed_token(x + (blk_tok + tid) * IND, layers[blk_tok + tid],
                fpw, fpb, lemb, fB, h);
    store_h16(sm, tid, h);
  }
  __syncthreads();

  for (int l = 0; l < NL; ++l) {
    const float* Wi = ipw + l * (3 * D) * D;
    const float* Bi = ipb + l * (3 * D);

    // ---------- phase 1: QKV GEMM via MFMA; wave = n-tile (6 of them) -------
    {
      const float sc = (wave < 2) ? 0.35355339059327373f : 1.0f;  // fold 1/sqrt(dh)
      const float bias = Bi[wave * 16 + n16] * sc;
      h4 Bf0, Bf1;
      {
        f4 w0 = *(const f4*)(Wi + (wave * 16 + n16) * D + quad * 4) * sc;
        f4 w1v = *(const f4*)(Wi + (wave * 16 + n16) * D + 16 + quad * 4) * sc;
        uint2 p0{pk2(w0.x, w0.y), pk2(w0.z, w0.w)};
        uint2 p1{pk2(w1v.x, w1v.y), pk2(w1v.z, w1v.w)};
        Bf0 = __builtin_bit_cast(h4, p0);
        Bf1 = __builtin_bit_cast(h4, p1);
      }
      for (int tt = 0; tt < 16; ++tt) {
        const int tokA = tt * 16 + n16;
        h4 A0 = *(const h4*)(sm + HOFF + tokA * 64 + ((quad ^ (tokA & 7)) * 8));
        h4 A1 = *(const h4*)(sm + HOFF + tokA * 64 + (((4 + quad) ^ (tokA & 7)) * 8));
        f4 C = __builtin_amdgcn_mfma_f32_16x16x16f16(
                   A0, Bf0, (f4){0.f, 0.f, 0.f, 0.f}, 0, 0, 0);
        C = __builtin_amdgcn_mfma_f32_16x16x16f16(A1, Bf1, C, 0, 0, 0);
        const int tokb = tt * 16 + quad * 4;
        const int feat = wave * 16 + n16;
#pragma unroll
        for (int r = 0; r < 4; ++r) {
          const int tok = tokb + r;
          __fp16 vh = (__fp16)(C[r] + bias);
          if (wave < 4) {  // Q (0..31) | K (32..63) -> QK buffer
            *(__fp16*)(sm + QKOFF + tok * 128 +
                       (((feat >> 3) ^ (tok & 7)) * 16) + (feat & 7) * 2) = vh;
          } else {         // V -> V^T
            const int vf = feat - 64;
            *(__fp16*)(sm + VOFF + vf * 512 +
                       ((tok >> 2) ^ ((vf & 7) << 1)) * 8 + (tok & 3) * 2) = vh;
          }
        }
      }
    }
    __syncthreads();

    // ---------- phase 2: flash attention; 6-wave split ----------------------
    if (wave < 4) {
      attn_head(sm, wave, 0, 10, n16, quad, qs);
    } else {
      attn_head(sm, (wave - 4) * 2,     10, 6, n16, quad, qs);
      attn_head(sm, (wave - 4) * 2 + 1, 10, 6, n16, quad, qs);
    }
    __syncthreads();

    // ---------- phase 3: out-proj + LN + FF + LN (token = thread 0..255) ----
    if (tid < S) {
      float acc[D];
      const uint4* orow = (const uint4*)(sm + HOFF + tid * 64);
#pragma unroll
      for (int c = 0; c < 4; ++c) {
        h8 v8 = __builtin_bit_cast(h8, orow[c]);
#pragma unroll
        for (int e = 0; e < 8; ++e) acc[c * 8 + e] = (float)v8[e];
      }
      post_token(l, h, acc, opw, opb, ln1g, ln1b, w1, b1, w2, b2, ln2g, ln2b);
      if (l != NL - 1) store_h16(sm, tid, h);  // own row: no cross-thread race
    }
    __syncthreads();
  }

  // ---------- final LN + head ----------
  if (tid < S) {
    lnorm(h, nog, nob);
    float* hs = (float*)sm;  // 25.6 KB staging over dead H/QK regions
#pragma unroll
    for (int o = 0; o < HOUT; ++o)
      hs[tid * HOUT + o] = dotp<16>(hw + o * D, h) + hb[o];
  }
  __syncthreads();
  f2* og = (f2*)(out + blk_tok * HOUT);
  const f2* os2 = (const f2*)sm;
  for (int i = tid; i < S * HOUT / 2; i += TPB) og[i] = os2[i];
}

extern "C" void kernel_launch(void* const* d_in, const int* in_sizes, int n_in,
                              void* d_out, int out_size, void* d_ws, size_t ws_size,
                              hipStream_t stream) {
  const float* x    = (const float*)d_in[0];
  const int*   lays = (const int*)  d_in[1];
  const float* fpw  = (const float*)d_in[2];
  const float* fpb  = (const float*)d_in[3];
  const float* lemb = (const float*)d_in[4];
  const float* fB   = (const float*)d_in[5];
  const float* ipw  = (const float*)d_in[6];
  const float* ipb  = (const float*)d_in[7];
  const float* opw  = (const float*)d_in[8];
  const float* opb  = (const float*)d_in[9];
  const float* ln1g = (const float*)d_in[10];
  const float* ln1b = (const float*)d_in[11];
  const float* w1   = (const float*)d_in[12];
  const float* b1   = (const float*)d_in[13];
  const float* w2   = (const float*)d_in[14];
  const float* b2   = (const float*)d_in[15];
  const float* ln2g = (const float*)d_in[16];
  const float* ln2b = (const float*)d_in[17];
  const float* nog  = (const float*)d_in[18];
  const float* nob  = (const float*)d_in[19];
  const float* hw   = (const float*)d_in[20];
  const float* hb   = (const float*)d_in[21];
  float* out = (float*)d_out;

  const int nwin = in_sizes[0] / (S * IND);  // 512 windows
  spai_fused<<<nwin, TPB, 0, stream>>>(x, lays, fpw, fpb, lemb, fB, ipw, ipb,
                                       opw, opb, ln1g, ln1b, w1, b1, w2, b2,
                                       ln2g, ln2b, nog, nob, hw, hb, out);
}

// Round 10
// 862.516 us; speedup vs baseline: 1.0712x; 1.0712x over previous
//
#include <hip/hip_runtime.h>

constexpr int S    = 256;
constexpr int D    = 32;
constexpr int NH   = 4;
constexpr int DH   = 8;
constexpr int DFF  = 64;
constexpr int NL   = 4;
constexpr int IND  = 58;
constexpr int HOUT = 25;
constexpr int TPB  = 384;  // 1 window/block, 6 waves -> 12 waves/CU (2 blocks)

typedef float  f2 __attribute__((ext_vector_type(2)));
typedef float  f4 __attribute__((ext_vector_type(4)));
typedef __fp16 h2 __attribute__((ext_vector_type(2)));
typedef __fp16 h4 __attribute__((ext_vector_type(4)));
typedef __fp16 h8 __attribute__((ext_vector_type(8)));

// LDS map (bytes), 64 KB total
constexpr int HOFF  = 0;      // h f16 [256][32] swizzled 8B-chunks; O reuses plain
constexpr int QKOFF = 16384;  // Q|K f16 [256 tok][64 feat], 16B-chunk XOR swizzle
constexpr int VOFF  = 49152;  // V^T 32 rows x 512 B, XOR-swizzled

__device__ __forceinline__ unsigned pk2(float a, float b) {
  h2 h = __builtin_amdgcn_cvt_pkrtz(a, b);
  return __builtin_bit_cast(unsigned, h);
}

// packed-fp32 dot (v_pk_fma_f32). All register-array loops must FULLY unroll
// (partial unroll -> scratch demotion, the round-3 251 MB regression).
template<int NF2>
__device__ __forceinline__ float dotp(const float* __restrict__ w,
                                      const float* __restrict__ v) {
  const f2* W = (const f2*)w;
  const f2* V = (const f2*)v;
  f2 a0 = {0.f, 0.f}, a1 = {0.f, 0.f};
#pragma unroll
  for (int i = 0; i < NF2; i += 2) a0 += V[i] * W[i];
#pragma unroll
  for (int i = 1; i < NF2; i += 2) a1 += V[i] * W[i];
  f2 s = a0 + a1;
  return s.x + s.y;
}

// tanh-approx GELU via exp (max dev ~3e-4, below bf16 floor; verified r7-r9)
__device__ __forceinline__ float gelu(float x) {
  float u = 1.5957691216057308f * fmaf(0.044715f * x * x, x, x);
  return x / (1.0f + __expf(-u));
}

__device__ __forceinline__ void lnorm(float* h, const float* __restrict__ g,
                                      const float* __restrict__ b) {
  float s = 0.f;
#pragma unroll
  for (int d = 0; d < D; ++d) s += h[d];
  const float m = s * (1.0f / D);
  float v = 0.f;
#pragma unroll
  for (int d = 0; d < D; ++d) { float c = h[d] - m; v = fmaf(c, c, v); }
  const float inv = rsqrtf(v * (1.0f / D) + 1e-5f);
#pragma unroll
  for (int d = 0; d < D; ++d) h[d] = (h[d] - m) * inv * g[d] + b[d];
}

__device__ __forceinline__ void embed_token(
    const float* __restrict__ xrow, int lay,
    const float* __restrict__ fpw, const float* __restrict__ fpb,
    const float* __restrict__ lemb, const float* __restrict__ fB,
    float* __restrict__ h) {
  float xr[IND];
  const f2* xv = (const f2*)xrow;
#pragma unroll
  for (int i = 0; i < 29; ++i) { f2 t = xv[i]; xr[2 * i] = t.x; xr[2 * i + 1] = t.y; }
  const float* le = lemb + lay * D;
  float pe[D];
#pragma unroll
  for (int k = 0; k < 16; ++k) {
    // sin(2*pi*t) = v_sin(fract(t)) -- hw sin takes revolutions; exact by
    // periodicity (verified r9: absmax unchanged).
    float t = xr[0] * fB[k] + xr[1] * fB[16 + k] + xr[2] * fB[32 + k];
#if __has_builtin(__builtin_amdgcn_sinf) && __has_builtin(__builtin_amdgcn_cosf) && __has_builtin(__builtin_amdgcn_fractf)
    float u = __builtin_amdgcn_fractf(t);
    pe[k]      = __builtin_amdgcn_sinf(u);
    pe[16 + k] = __builtin_amdgcn_cosf(u);
#else
    float sv, cv;
    sincosf(6.2831853071795864f * (t - floorf(t)), &sv, &cv);
    pe[k] = sv; pe[16 + k] = cv;
#endif
  }
#pragma unroll
  for (int d = 0; d < D; ++d)
    h[d] = dotp<29>(fpw + d * IND, xr) + fpb[d] + le[d] + pe[d];
}

__device__ __forceinline__ void post_token(
    int l, float* __restrict__ h, const float* __restrict__ acc,
    const float* __restrict__ opw, const float* __restrict__ opb,
    const float* __restrict__ ln1g, const float* __restrict__ ln1b,
    const float* __restrict__ w1, const float* __restrict__ b1,
    const float* __restrict__ w2, const float* __restrict__ b2,
    const float* __restrict__ ln2g, const float* __restrict__ ln2b) {
  const float* Wo = opw + l * D * D;
  const float* Bo = opb + l * D;
#pragma unroll
  for (int o = 0; o < D; ++o) h[o] += dotp<16>(Wo + o * D, acc) + Bo[o];
  lnorm(h, ln1g + l * D, ln1b + l * D);
  const float* Wa = w1 + l * DFF * D;
  const float* Ba = b1 + l * DFF;
  float tt[DFF];
#pragma unroll
  for (int j = 0; j < DFF; ++j)
    tt[j] = gelu(dotp<16>(Wa + j * D, h) + Ba[j]);
  const float* Wb = w2 + l * D * DFF;
  const float* Bb = b2 + l * D;
#pragma unroll
  for (int d = 0; d < D; ++d) h[d] += dotp<32>(Wb + d * DFF, tt) + Bb[d];
  lnorm(h, ln2g + l * D, ln2b + l * D);
}

__device__ __forceinline__ void store_h16(unsigned char* sm, int tok,
                                          const float* __restrict__ h) {
#pragma unroll
  for (int c = 0; c < 8; ++c) {
    uint2 p{pk2(h[4 * c], h[4 * c + 1]), pk2(h[4 * c + 2], h[4 * c + 3])};
    *(uint2*)(sm + HOFF + tok * 64 + ((c ^ (tok & 7)) * 8)) = p;
  }
}

// One head's flash attention over it-tiles [it0, it0+itn).
__device__ __forceinline__ void attn_head(unsigned char* sm, int hh, int it0,
                                          int itn, int m, int quad, int qs) {
  h4 Af[16];  // K A-frags; quads 2,3 = dh 8->16 zero pad
#pragma unroll
  for (int jt = 0; jt < 16; ++jt) {
    const int tok = jt * 16 + m;
    uint2 a = *(const uint2*)(sm + QKOFF + tok * 128 +
                              (((4 + hh) ^ (tok & 7)) * 16) + qs * 8);
    if (quad >= 2) { a.x = 0u; a.y = 0u; }
    Af[jt] = __builtin_bit_cast(h4, a);
  }
  const int vbase = VOFF + (hh * 8 + (m & 7)) * 512;
  const int vkey  = (m & 7) << 1;

  for (int ii = 0; ii < itn; ++ii) {
    const int it = it0 + ii;
    const int ti = it * 16 + m;
    h4 Qf = *(const h4*)(sm + QKOFF + ti * 128 + ((hh ^ (ti & 7)) * 16) + qs * 8);
    f4 Of0 = {0.f, 0.f, 0.f, 0.f}, Of1 = {0.f, 0.f, 0.f, 0.f};
    float ls0 = 0.f, ls1 = 0.f;
#pragma unroll
    for (int jt = 0; jt < 16; ++jt) {
      // T[j,i] = K.Q^T: C col = i (lane&15), row = j (quad*4+r)
      f4 T = __builtin_amdgcn_mfma_f32_16x16x16f16(
                 Af[jt], Qf, (f4){0.f, 0.f, 0.f, 0.f}, 0, 0, 0);
      float e0 = __expf(T[0]), e1 = __expf(T[1]);
      float e2 = __expf(T[2]), e3 = __expf(T[3]);
      uint2 pu{pk2(e0, e1), pk2(e2, e3)};
      h4 P = __builtin_bit_cast(h4, pu);  // C-frag of T == A-frag of P
      h4 Bv = *(const h4*)(sm + vbase + (((jt * 4 + quad) ^ vkey) * 8));
      if (jt & 1) {  // dual accumulators: halve the PV/lsum dep chains
        ls1 += (e0 + e1) + (e2 + e3);
        Of1 = __builtin_amdgcn_mfma_f32_16x16x16f16(P, Bv, Of1, 0, 0, 0);
      } else {
        ls0 += (e0 + e1) + (e2 + e3);
        Of0 = __builtin_amdgcn_mfma_f32_16x16x16f16(P, Bv, Of0, 0, 0, 0);
      }
    }
    float lsum = ls0 + ls1;
    f4 Of = Of0 + Of1;
    lsum += __shfl_xor(lsum, 16);
    lsum += __shfl_xor(lsum, 32);
#pragma unroll
    for (int r = 0; r < 4; ++r) {
      float ls = __builtin_bit_cast(
          float, __builtin_amdgcn_ds_bpermute(
                     (quad * 4 + r) << 2, __builtin_bit_cast(int, lsum)));
      float o = Of[r] * __builtin_amdgcn_rcpf(ls);
      if (m < 8) {  // O -> plain [tok][32 f16] over dead h-f16 region
        const int t2 = it * 16 + quad * 4 + r;
        *(__fp16*)(sm + HOFF + t2 * 64 + (hh * 8 + m) * 2) = (__fp16)o;
      }
    }
  }
}

// launch_bounds 2nd arg: ONLY values 1-2 are safe here. Measured on this
// kernel family: (256,2)->VGPR 120-128 no spill; (512,4)->64, (512,3)->84,
// (384,3)->84, all with 100+ MB scratch spills. Natural footprint ~120.
// With arg=2 (cap 256) the allocator lands ~120-140; runtime occupancy is
// then LDS-limited: 2 blocks x 6 waves = 12 waves/CU = 3 waves/SIMD.
__global__ void __launch_bounds__(TPB, 2)
spai_fused(const float* __restrict__ x,    const int*   __restrict__ layers,
           const float* __restrict__ fpw,  const float* __restrict__ fpb,
           const float* __restrict__ lemb, const float* __restrict__ fB,
           const float* __restrict__ ipw,  const float* __restrict__ ipb,
           const float* __restrict__ opw,  const float* __restrict__ opb,
           const float* __restrict__ ln1g, const float* __restrict__ ln1b,
           const float* __restrict__ w1,   const float* __restrict__ b1,
           const float* __restrict__ w2,   const float* __restrict__ b2,
           const float* __restrict__ ln2g, const float* __restrict__ ln2b,
           const float* __restrict__ nog,  const float* __restrict__ nob,
           const float* __restrict__ hw,   const float* __restrict__ hb,
           float* __restrict__ out) {
  __shared__ __align__(16) unsigned char sm[65536];
  const int tid  = threadIdx.x;
  const int lane = tid & 63;
  const int wave = tid >> 6;   // 0..5
  const int n16  = lane & 15;
  const int quad = lane >> 4;
  const int qs   = quad & 1;
  const size_t blk_tok = (size_t)blockIdx.x * S;

  float h[D];
  if (tid < S) {
    embed_token(x + (blk_tok + tid) * IND, layers[blk_tok + tid],
                fpw, fpb, lemb, fB, h);
    store_h16(sm, tid, h);
  }
  __syncthreads();

  for (int l = 0; l < NL; ++l) {
    const float* Wi = ipw + l * (3 * D) * D;
    const float* Bi = ipb + l * (3 * D);

    // ---------- phase 1: QKV GEMM via MFMA; wave = n-tile (6 of them) -------
    {
      const float sc = (wave < 2) ? 0.35355339059327373f : 1.0f;  // fold 1/sqrt(dh)
      const float bias = Bi[wave * 16 + n16] * sc;
      h4 Bf0, Bf1;
      {
        f4 w0 = *(const f4*)(Wi + (wave * 16 + n16) * D + quad * 4) * sc;
        f4 w1v = *(const f4*)(Wi + (wave * 16 + n16) * D + 16 + quad * 4) * sc;
        uint2 p0{pk2(w0.x, w0.y), pk2(w0.z, w0.w)};
        uint2 p1{pk2(w1v.x, w1v.y), pk2(w1v.z, w1v.w)};
        Bf0 = __builtin_bit_cast(h4, p0);
        Bf1 = __builtin_bit_cast(h4, p1);
      }
      for (int tt = 0; tt < 16; ++tt) {
        const int tokA = tt * 16 + n16;
        h4 A0 = *(const h4*)(sm + HOFF + tokA * 64 + ((quad ^ (tokA & 7)) * 8));
        h4 A1 = *(const h4*)(sm + HOFF + tokA * 64 + (((4 + quad) ^ (tokA & 7)) * 8));
        f4 C = __builtin_amdgcn_mfma_f32_16x16x16f16(
                   A0, Bf0, (f4){0.f, 0.f, 0.f, 0.f}, 0, 0, 0);
        C = __builtin_amdgcn_mfma_f32_16x16x16f16(A1, Bf1, C, 0, 0, 0);
        const int tokb = tt * 16 + quad * 4;
        const int feat = wave * 16 + n16;
#pragma unroll
        for (int r = 0; r < 4; ++r) {
          const int tok = tokb + r;
          __fp16 vh = (__fp16)(C[r] + bias);
          if (wave < 4) {  // Q (0..31) | K (32..63) -> QK buffer
            *(__fp16*)(sm + QKOFF + tok * 128 +
                       (((feat >> 3) ^ (tok & 7)) * 16) + (feat & 7) * 2) = vh;
          } else {         // V -> V^T
            const int vf = feat - 64;
            *(__fp16*)(sm + VOFF + vf * 512 +
                       ((tok >> 2) ^ ((vf & 7) << 1)) * 8 + (tok & 3) * 2) = vh;
          }
        }
      }
    }
    __syncthreads();

    // ---------- phase 2: flash attention; 6-wave split ----------------------
    if (wave < 4) {
      attn_head(sm, wave, 0, 10, n16, quad, qs);
    } else {
      attn_head(sm, (wave - 4) * 2,     10, 6, n16, quad, qs);
      attn_head(sm, (wave - 4) * 2 + 1, 10, 6, n16, quad, qs);
    }
    __syncthreads();

    // ---------- phase 3: out-proj + LN + FF + LN (token = thread 0..255) ----
    if (tid < S) {
      float acc[D];
      const uint4* orow = (const uint4*)(sm + HOFF + tid * 64);
#pragma unroll
      for (int c = 0; c < 4; ++c) {
        h8 v8 = __builtin_bit_cast(h8, orow[c]);
#pragma unroll
        for (int e = 0; e < 8; ++e) acc[c * 8 + e] = (float)v8[e];
      }
      post_token(l, h, acc, opw, opb, ln1g, ln1b, w1, b1, w2, b2, ln2g, ln2b);
      if (l != NL - 1) store_h16(sm, tid, h);  // own row: no cross-thread race
    }
    __syncthreads();
  }

  // ---------- final LN + head ----------
  if (tid < S) {
    lnorm(h, nog, nob);
    float* hs = (float*)sm;  // 25.6 KB staging over dead H/QK regions
#pragma unroll
    for (int o = 0; o < HOUT; ++o)
      hs[tid * HOUT + o] = dotp<16>(hw + o * D, h) + hb[o];
  }
  __syncthreads();
  f2* og = (f2*)(out + blk_tok * HOUT);
  const f2* os2 = (const f2*)sm;
  for (int i = tid; i < S * HOUT / 2; i += TPB) og[i] = os2[i];
}

extern "C" void kernel_launch(void* const* d_in, const int* in_sizes, int n_in,
                              void* d_out, int out_size, void* d_ws, size_t ws_size,
                              hipStream_t stream) {
  const float* x    = (const float*)d_in[0];
  const int*   lays = (const int*)  d_in[1];
  const float* fpw  = (const float*)d_in[2];
  const float* fpb  = (const float*)d_in[3];
  const float* lemb = (const float*)d_in[4];
  const float* fB   = (const float*)d_in[5];
  const float* ipw  = (const float*)d_in[6];
  const float* ipb  = (const float*)d_in[7];
  const float* opw  = (const float*)d_in[8];
  const float* opb  = (const float*)d_in[9];
  const float* ln1g = (const float*)d_in[10];
  const float* ln1b = (const float*)d_in[11];
  const float* w1   = (const float*)d_in[12];
  const float* b1   = (const float*)d_in[13];
  const float* w2   = (const float*)d_in[14];
  const float* b2   = (const float*)d_in[15];
  const float* ln2g = (const float*)d_in[16];
  const float* ln2b = (const float*)d_in[17];
  const float* nog  = (const float*)d_in[18];
  const float* nob  = (const float*)d_in[19];
  const float* hw   = (const float*)d_in[20];
  const float* hb   = (const float*)d_in[21];
  float* out = (float*)d_out;

  const int nwin = in_sizes[0] / (S * IND);  // 512 windows
  spai_fused<<<nwin, TPB, 0, stream>>>(x, lays, fpw, fpb, lemb, fB, ipw, ipb,
                                       opw, opb, ln1g, ln1b, w1, b1, w2, b2,
                                       ln2g, ln2b, nog, nob, hw, hb, out);
}

// Round 11
// 306.853 us; speedup vs baseline: 3.0110x; 2.8108x over previous
//
#include <hip/hip_runtime.h>

constexpr int S    = 256;
constexpr int D    = 32;
constexpr int NH   = 4;
constexpr int DH   = 8;
constexpr int DFF  = 64;
constexpr int NL   = 4;
constexpr int IND  = 58;
constexpr int HOUT = 25;
constexpr int TPB  = 256;  // 1 window/block, 4 waves; 2 blocks/CU (proven shell)

typedef float  f2 __attribute__((ext_vector_type(2)));
typedef float  f4 __attribute__((ext_vector_type(4)));
typedef __fp16 h2 __attribute__((ext_vector_type(2)));
typedef __fp16 h4 __attribute__((ext_vector_type(4)));
typedef __fp16 h8 __attribute__((ext_vector_type(8)));

// LDS map (bytes), 64 KB. Liveness per layer:
//  HOFF: h f16 (ph1 A) -> attn O (ph2 out, GEMM2 A) -> h' f16 (GEMM3 A)
//  QKOFF: Q|K (ph2) -> t = gelu f16 [256][64] (GEMM4 A)
//  VOFF: V^T (ph2) -> O' f16 (LN1 in) -> O'' f16 (LN2 in)
constexpr int HOFF  = 0;      // 16 KB  [256][32] f16, 8B chunks ^(tok&7)
constexpr int QKOFF = 16384;  // 32 KB
constexpr int VOFF  = 49152;  // 16 KB  [256][32] f16, 8B chunks ^(tok&7)

__device__ __forceinline__ unsigned pk2(float a, float b) {
  h2 h = __builtin_amdgcn_cvt_pkrtz(a, b);
  return __builtin_bit_cast(unsigned, h);
}

// packed-fp32 dot. All register-array loops must FULLY unroll (r3 lesson).
template<int NF2>
__device__ __forceinline__ float dotp(const float* __restrict__ w,
                                      const float* __restrict__ v) {
  const f2* W = (const f2*)w;
  const f2* V = (const f2*)v;
  f2 a0 = {0.f, 0.f}, a1 = {0.f, 0.f};
#pragma unroll
  for (int i = 0; i < NF2; i += 2) a0 += V[i] * W[i];
#pragma unroll
  for (int i = 1; i < NF2; i += 2) a1 += V[i] * W[i];
  f2 s = a0 + a1;
  return s.x + s.y;
}

// tanh-approx GELU via exp (max dev ~3e-4; verified r7-r10 absmax unchanged)
__device__ __forceinline__ float gelu(float x) {
  float u = 1.5957691216057308f * fmaf(0.044715f * x * x, x, x);
  return x / (1.0f + __expf(-u));
}

__device__ __forceinline__ void lnorm(float* h, const float* __restrict__ g,
                                      const float* __restrict__ b) {
  float s = 0.f;
#pragma unroll
  for (int d = 0; d < D; ++d) s += h[d];
  const float m = s * (1.0f / D);
  float v = 0.f;
#pragma unroll
  for (int d = 0; d < D; ++d) { float c = h[d] - m; v = fmaf(c, c, v); }
  const float inv = rsqrtf(v * (1.0f / D) + 1e-5f);
#pragma unroll
  for (int d = 0; d < D; ++d) h[d] = (h[d] - m) * inv * g[d] + b[d];
}

__device__ __forceinline__ void embed_token(
    const float* __restrict__ xrow, int lay,
    const float* __restrict__ fpw, const float* __restrict__ fpb,
    const float* __restrict__ lemb, const float* __restrict__ fB,
    float* __restrict__ h) {
  float xr[IND];
  const f2* xv = (const f2*)xrow;
#pragma unroll
  for (int i = 0; i < 29; ++i) { f2 t = xv[i]; xr[2 * i] = t.x; xr[2 * i + 1] = t.y; }
  const float* le = lemb + lay * D;
  float pe[D];
#pragma unroll
  for (int k = 0; k < 16; ++k) {
    // sin(2*pi*t) = v_sin(fract(t)) in revolutions (verified r9/r10)
    float t = xr[0] * fB[k] + xr[1] * fB[16 + k] + xr[2] * fB[32 + k];
#if __has_builtin(__builtin_amdgcn_sinf) && __has_builtin(__builtin_amdgcn_cosf) && __has_builtin(__builtin_amdgcn_fractf)
    float u = __builtin_amdgcn_fractf(t);
    pe[k]      = __builtin_amdgcn_sinf(u);
    pe[16 + k] = __builtin_amdgcn_cosf(u);
#else
    float sv, cv;
    sincosf(6.2831853071795864f * (t - floorf(t)), &sv, &cv);
    pe[k] = sv; pe[16 + k] = cv;
#endif
  }
#pragma unroll
  for (int d = 0; d < D; ++d)
    h[d] = dotp<29>(fpw + d * IND, xr) + fpb[d] + le[d] + pe[d];
}

// ---- shared fragment helpers (layouts verified by r8's working ph1) ----
// B-frag from f32 weight row-major [N][K]: lane n16 = row, kh = 16-wide k-half
__device__ __forceinline__ h4 bfrag(const float* __restrict__ W, int row,
                                    int K, int kh, int quad) {
  f4 w = *(const f4*)(W + row * K + kh * 16 + quad * 4);
  uint2 p{pk2(w.x, w.y), pk2(w.z, w.w)};
  return __builtin_bit_cast(h4, p);
}
// A-frag from [tok][32] f16, 8B chunks swizzled ^(tok&7)
__device__ __forceinline__ h4 afrag32(const unsigned char* sm, int base,
                                      int tok, int kh, int quad) {
  return *(const h4*)(sm + base + tok * 64 + (((kh * 4 + quad) ^ (tok & 7)) * 8));
}
// scalar C-element scatter into [tok][32] f16 swizzled layout
__device__ __forceinline__ void cstore32(unsigned char* sm, int base, int tok,
                                         int feat, float v) {
  *(__fp16*)(sm + base + tok * 64 + (((feat >> 2) ^ (tok & 7)) * 8) +
             (feat & 3) * 2) = (__fp16)v;
}

// Write this thread's h (f32 regs) as swizzled f16 row into HOFF.
__device__ __forceinline__ void store_h16(unsigned char* sm, int tok,
                                          const float* __restrict__ h) {
#pragma unroll
  for (int c = 0; c < 8; ++c) {
    uint2 p{pk2(h[4 * c], h[4 * c + 1]), pk2(h[4 * c + 2], h[4 * c + 3])};
    *(uint2*)(sm + HOFF + tok * 64 + ((c ^ (tok & 7)) * 8)) = p;
  }
}
// Read a swizzled [tok][32] f16 row, accumulate into h (residual add).
__device__ __forceinline__ void add_row32(const unsigned char* sm, int base,
                                          int tok, float* __restrict__ h) {
#pragma unroll
  for (int c = 0; c < 8; ++c) {
    h4 q = *(const h4*)(sm + base + tok * 64 + ((c ^ (tok & 7)) * 8));
#pragma unroll
    for (int e = 0; e < 4; ++e) h[4 * c + e] += (float)q[e];
  }
}

// launch_bounds: ONLY (256,2) is spill-free for this family (measured r5-r10:
// 384/512-thread variants spill 30-700 MB regardless of bounds arg).
__global__ void __launch_bounds__(TPB, 2)
spai_fused(const float* __restrict__ x,    const int*   __restrict__ layers,
           const float* __restrict__ fpw,  const float* __restrict__ fpb,
           const float* __restrict__ lemb, const float* __restrict__ fB,
           const float* __restrict__ ipw,  const float* __restrict__ ipb,
           const float* __restrict__ opw,  const float* __restrict__ opb,
           const float* __restrict__ ln1g, const float* __restrict__ ln1b,
           const float* __restrict__ w1,   const float* __restrict__ b1,
           const float* __restrict__ w2,   const float* __restrict__ b2,
           const float* __restrict__ ln2g, const float* __restrict__ ln2b,
           const float* __restrict__ nog,  const float* __restrict__ nob,
           const float* __restrict__ hw,   const float* __restrict__ hb,
           float* __restrict__ out) {
  __shared__ __align__(16) unsigned char sm[65536];
  const int tid  = threadIdx.x;
  const int lane = tid & 63;
  const int wave = tid >> 6;   // 0..3
  const int n16  = lane & 15;
  const int quad = lane >> 4;
  const int qs   = quad & 1;
  const size_t blk_tok = (size_t)blockIdx.x * S;

  float h[D];
  embed_token(x + (blk_tok + tid) * IND, layers[blk_tok + tid],
              fpw, fpb, lemb, fB, h);
  store_h16(sm, tid, h);
  __syncthreads();

  for (int l = 0; l < NL; ++l) {
    const float* Wi = ipw + l * (3 * D) * D;
    const float* Bi = ipb + l * (3 * D);

    // ---- ph1: QKV GEMM (r8-verified); wave -> token tiles wave*4..+4 ------
    {
      h4 Bf[12]; float bias[6];
#pragma unroll
      for (int nt = 0; nt < 6; ++nt) {
        const float sc = (nt < 2) ? 0.35355339059327373f : 1.0f;  // 1/sqrt(dh)
        bias[nt] = Bi[nt * 16 + n16] * sc;
#pragma unroll
        for (int kh = 0; kh < 2; ++kh) {
          f4 wv = *(const f4*)(Wi + (nt * 16 + n16) * D + kh * 16 + quad * 4) * sc;
          uint2 wp{pk2(wv.x, wv.y), pk2(wv.z, wv.w)};
          Bf[nt * 2 + kh] = __builtin_bit_cast(h4, wp);
        }
      }
      h4 Ah[8];
#pragma unroll
      for (int it = 0; it < 4; ++it) {
        const int tok = (wave * 4 + it) * 16 + n16;
        Ah[it * 2]     = afrag32(sm, HOFF, tok, 0, quad);
        Ah[it * 2 + 1] = afrag32(sm, HOFF, tok, 1, quad);
      }
#pragma unroll
      for (int it = 0; it < 4; ++it) {
        const int tokb = (wave * 4 + it) * 16 + quad * 4;
#pragma unroll
        for (int nt = 0; nt < 6; ++nt) {
          f4 C = __builtin_amdgcn_mfma_f32_16x16x16f16(
                     Ah[it * 2], Bf[nt * 2], (f4){0.f, 0.f, 0.f, 0.f}, 0, 0, 0);
          C = __builtin_amdgcn_mfma_f32_16x16x16f16(
                  Ah[it * 2 + 1], Bf[nt * 2 + 1], C, 0, 0, 0);
          const int feat = nt * 16 + n16;
#pragma unroll
          for (int r = 0; r < 4; ++r) {
            const int tok = tokb + r;
            __fp16 vh = (__fp16)(C[r] + bias[nt]);
            if (nt < 4) {  // Q|K -> QK buffer (r8 layout)
              *(__fp16*)(sm + QKOFF + tok * 128 +
                         (((feat >> 3) ^ (tok & 7)) * 16) + (feat & 7) * 2) = vh;
            } else {       // V -> V^T (r8 layout)
              const int vf = feat - 64;
              *(__fp16*)(sm + VOFF + vf * 512 +
                         ((tok >> 2) ^ ((vf & 7) << 1)) * 8 + (tok & 3) * 2) = vh;
            }
          }
        }
      }
    }
    __syncthreads();

    // ---- ph2: flash attention (wave = head), dual accumulators ------------
    {
      const int hh = wave;
      const int m  = n16;
      h4 Af[16];  // K A-frags; quads 2,3 = dh 8->16 zero pad
#pragma unroll
      for (int jt = 0; jt < 16; ++jt) {
        const int tok = jt * 16 + m;
        uint2 a = *(const uint2*)(sm + QKOFF + tok * 128 +
                                  (((4 + hh) ^ (tok & 7)) * 16) + qs * 8);
        if (quad >= 2) { a.x = 0u; a.y = 0u; }
        Af[jt] = __builtin_bit_cast(h4, a);
      }
      const int vbase = VOFF + (hh * 8 + (m & 7)) * 512;
      const int vkey  = (m & 7) << 1;

#pragma unroll 2
      for (int it = 0; it < 16; ++it) {
        const int ti = it * 16 + m;
        h4 Qf = *(const h4*)(sm + QKOFF + ti * 128 + ((hh ^ (ti & 7)) * 16) + qs * 8);
        f4 Of0 = {0.f, 0.f, 0.f, 0.f}, Of1 = {0.f, 0.f, 0.f, 0.f};
        float ls0 = 0.f, ls1 = 0.f;
#pragma unroll
        for (int jt = 0; jt < 16; ++jt) {
          f4 T = __builtin_amdgcn_mfma_f32_16x16x16f16(
                     Af[jt], Qf, (f4){0.f, 0.f, 0.f, 0.f}, 0, 0, 0);
          float e0 = __expf(T[0]), e1 = __expf(T[1]);
          float e2 = __expf(T[2]), e3 = __expf(T[3]);
          uint2 pu{pk2(e0, e1), pk2(e2, e3)};
          h4 P = __builtin_bit_cast(h4, pu);  // C-frag of T == A-frag of P
          h4 Bv = *(const h4*)(sm + vbase + (((jt * 4 + quad) ^ vkey) * 8));
          if (jt & 1) {
            ls1 += (e0 + e1) + (e2 + e3);
            Of1 = __builtin_amdgcn_mfma_f32_16x16x16f16(P, Bv, Of1, 0, 0, 0);
          } else {
            ls0 += (e0 + e1) + (e2 + e3);
            Of0 = __builtin_amdgcn_mfma_f32_16x16x16f16(P, Bv, Of0, 0, 0, 0);
          }
        }
        float lsum = ls0 + ls1;
        f4 Of = Of0 + Of1;
        lsum += __shfl_xor(lsum, 16);
        lsum += __shfl_xor(lsum, 32);
#pragma unroll
        for (int r = 0; r < 4; ++r) {
          float ls = __builtin_bit_cast(
              float, __builtin_amdgcn_ds_bpermute(
                         (quad * 4 + r) << 2, __builtin_bit_cast(int, lsum)));
          float o = Of[r] * __builtin_amdgcn_rcpf(ls);
          if (m < 8)  // O -> HOFF swizzled [tok][32] (h f16 dead after ph1)
            cstore32(sm, HOFF, it * 16 + quad * 4 + r, hh * 8 + m, o);
        }
      }
    }
    __syncthreads();

    // ---- GEMM2: O' = O_attn x Wo^T + Bo -> VOFF (V dead) ------------------
    {
      const float* Wo = opw + l * D * D;
      const float* Bo = opb + l * D;
      h4 Bf[4]; float bs[2];
#pragma unroll
      for (int nt = 0; nt < 2; ++nt) {
        bs[nt] = Bo[nt * 16 + n16];
#pragma unroll
        for (int kh = 0; kh < 2; ++kh)
          Bf[nt * 2 + kh] = bfrag(Wo, nt * 16 + n16, 32, kh, quad);
      }
#pragma unroll
      for (int ii = 0; ii < 4; ++ii) {
        const int it = wave * 4 + ii;
        h4 A0 = afrag32(sm, HOFF, it * 16 + n16, 0, quad);
        h4 A1 = afrag32(sm, HOFF, it * 16 + n16, 1, quad);
#pragma unroll
        for (int nt = 0; nt < 2; ++nt) {
          f4 C = __builtin_amdgcn_mfma_f32_16x16x16f16(
                     A0, Bf[nt * 2], (f4){0.f, 0.f, 0.f, 0.f}, 0, 0, 0);
          C = __builtin_amdgcn_mfma_f32_16x16x16f16(A1, Bf[nt * 2 + 1], C, 0, 0, 0);
#pragma unroll
          for (int r = 0; r < 4; ++r)
            cstore32(sm, VOFF, it * 16 + quad * 4 + r, nt * 16 + n16, C[r] + bs[nt]);
        }
      }
    }
    __syncthreads();

    // ---- token: h += O'; LN1; h' f16 -> HOFF ------------------------------
    add_row32(sm, VOFF, tid, h);
    lnorm(h, ln1g + l * D, ln1b + l * D);
    store_h16(sm, tid, h);
    __syncthreads();

    // ---- GEMM3: t = gelu(h' x Wa^T + Ba) -> QKOFF [256][64] f16 -----------
    {
      const float* Wa = w1 + l * DFF * D;
      const float* Ba = b1 + l * DFF;
      const int nt = wave;  // 4 waves = 4 n-tiles of 64 outputs
      const float bs = Ba[nt * 16 + n16];
      h4 B0 = bfrag(Wa, nt * 16 + n16, 32, 0, quad);
      h4 B1 = bfrag(Wa, nt * 16 + n16, 32, 1, quad);
      const int feat = nt * 16 + n16;
#pragma unroll 4
      for (int it = 0; it < 16; ++it) {
        h4 A0 = afrag32(sm, HOFF, it * 16 + n16, 0, quad);
        h4 A1 = afrag32(sm, HOFF, it * 16 + n16, 1, quad);
        f4 C = __builtin_amdgcn_mfma_f32_16x16x16f16(
                   A0, B0, (f4){0.f, 0.f, 0.f, 0.f}, 0, 0, 0);
        C = __builtin_amdgcn_mfma_f32_16x16x16f16(A1, B1, C, 0, 0, 0);
#pragma unroll
        for (int r = 0; r < 4; ++r) {
          const int tok = it * 16 + quad * 4 + r;
          // t layout: [tok][64] f16, 8B chunks ^(tok&15)
          *(__fp16*)(sm + QKOFF + tok * 128 +
                     (((feat >> 2) ^ (tok & 15)) * 8) + (feat & 3) * 2) =
              (__fp16)gelu(C[r] + bs);
        }
      }
    }
    __syncthreads();

    // ---- GEMM4: O'' = t x Wb^T + Bb -> VOFF (O' dead) ---------------------
    {
      const float* Wb = w2 + l * D * DFF;
      const float* Bb = b2 + l * D;
      h4 Bf[8]; float bs[2];
#pragma unroll
      for (int nt = 0; nt < 2; ++nt) {
        bs[nt] = Bb[nt * 16 + n16];
#pragma unroll
        for (int kh = 0; kh < 4; ++kh)
          Bf[nt * 4 + kh] = bfrag(Wb, nt * 16 + n16, 64, kh, quad);
      }
#pragma unroll
      for (int ii = 0; ii < 4; ++ii) {
        const int it = wave * 4 + ii;
        const int tokA = it * 16 + n16;
        h4 A[4];
#pragma unroll
        for (int kh = 0; kh < 4; ++kh)
          A[kh] = *(const h4*)(sm + QKOFF + tokA * 128 +
                               (((kh * 4 + quad) ^ (tokA & 15)) * 8));
#pragma unroll
        for (int nt = 0; nt < 2; ++nt) {
          f4 C = {0.f, 0.f, 0.f, 0.f};
#pragma unroll
          for (int kh = 0; kh < 4; ++kh)
            C = __builtin_amdgcn_mfma_f32_16x16x16f16(A[kh], Bf[nt * 4 + kh], C,
                                                      0, 0, 0);
#pragma unroll
          for (int r = 0; r < 4; ++r)
            cstore32(sm, VOFF, it * 16 + quad * 4 + r, nt * 16 + n16, C[r] + bs[nt]);
        }
      }
    }
    __syncthreads();

    // ---- token: h += O''; LN2; h f16 -> HOFF (next layer's ph1 A) ---------
    add_row32(sm, VOFF, tid, h);
    lnorm(h, ln2g + l * D, ln2b + l * D);
    store_h16(sm, tid, h);
    __syncthreads();
  }

  // ---------- final LN + head ----------
  lnorm(h, nog, nob);
  float* hs = (float*)sm;  // 25.6 KB staging over dead HOFF+QKOFF
#pragma unroll
  for (int o = 0; o < HOUT; ++o)
    hs[tid * HOUT + o] = dotp<16>(hw + o * D, h) + hb[o];
  __syncthreads();
  f2* og = (f2*)(out + blk_tok * HOUT);
  const f2* os2 = (const f2*)hs;
  for (int i = tid; i < S * HOUT / 2; i += TPB) og[i] = os2[i];
}

extern "C" void kernel_launch(void* const* d_in, const int* in_sizes, int n_in,
                              void* d_out, int out_size, void* d_ws, size_t ws_size,
                              hipStream_t stream) {
  const float* x    = (const float*)d_in[0];
  const int*   lays = (const int*)  d_in[1];
  const float* fpw  = (const float*)d_in[2];
  const float* fpb  = (const float*)d_in[3];
  const float* lemb = (const float*)d_in[4];
  const float* fB   = (const float*)d_in[5];
  const float* ipw  = (const float*)d_in[6];
  const float* ipb  = (const float*)d_in[7];
  const float* opw  = (const float*)d_in[8];
  const float* opb  = (const float*)d_in[9];
  const float* ln1g = (const float*)d_in[10];
  const float* ln1b = (const float*)d_in[11];
  const float* w1   = (const float*)d_in[12];
  const float* b1   = (const float*)d_in[13];
  const float* w2   = (const float*)d_in[14];
  const float* b2   = (const float*)d_in[15];
  const float* ln2g = (const float*)d_in[16];
  const float* ln2b = (const float*)d_in[17];
  const float* nog  = (const float*)d_in[18];
  const float* nob  = (const float*)d_in[19];
  const float* hw   = (const float*)d_in[20];
  const float* hb   = (const float*)d_in[21];
  float* out = (float*)d_out;

  const int nwin = in_sizes[0] / (S * IND);  // 512 windows
  spai_fused<<<nwin, TPB, 0, stream>>>(x, lays, fpw, fpb, lemb, fB, ipw, ipb,
                                       opw, opb, ln1g, ln1b, w1, b1, w2, b2,
                                       ln2g, ln2b, nog, nob, hw, hb, out);
}